// Round 4
// baseline (14942.763 us; speedup 1.0000x reference)
//
#include <hip/hip_runtime.h>

// GRU scan, 2 layers, B=64 T=4096 D=H=128 — ANTIPHASE layer-specialized waves.
// 4 persistent WGs x 16 batch rows x 512 threads (8 waves).
// Waves 0-3 = layer 0, waves 4-7 = layer 1. Wave i runs on SIMD i&3, so each
// SIMD hosts one L0 + one L1 wave.
//
// v5: v1's per-wave code (7030us best), but the two wave groups run in
// ANTIPHASE so MFMA and VALU phases overlap on each SIMD:
//   region A (t): L0: P1(t)=24 hMFMA          L1: P2'(s=t-3)=gates+24 iMFMA
//   region B (t): L0: P2(t)=gates+24 iMFMA    L1: P1'(s=t-2)=24 hMFMA
// v1 ran both groups in the same phase -> MfmaUtil(37%)+VALUBusy(52%)~=89%
// serial sum. Antiphase puts ~48 MFMA + one wave's gates in EVERY barrier
// interval per SIMD.
// Hazards (2-buffer parity, all >=1 barrier apart):
//   L0 writes h0(t)@par in B(t); readers: L0-P1(t+1)@A reads parx,
//     L1-P2'@A(t+... ) reads H0@par BEFORE B(t) overwrite (A precedes B).
//   L1 writes h1(s)@parx in A(t); reader L1-P1'@B(t) reads parx (1 barrier).
//   X: L0-only. Stage x(t+2)->X@par in B(t); consumed B(t+1) reads parx.
// Per-wave body, math, LDS layout = v1 verbatim (rounds 1-3 lessons: don't
// hand-interleave, don't merge barriers, linear LDS).

#define Tlen 4096
#define Hd   128
#define Bsz  64

typedef __attribute__((ext_vector_type(8))) short short8;     // 8 bf16
typedef __attribute__((ext_vector_type(4))) short short4v;    // 4 bf16
typedef __attribute__((ext_vector_type(4))) float float4v;
typedef __attribute__((ext_vector_type(4))) unsigned int uint4v;

#define MFMA16(a, b, c) __builtin_amdgcn_mfma_f32_16x16x32_bf16((a), (b), (c), 0, 0, 0)

static __device__ __forceinline__ float fast_exp2(float x) {
#if __has_builtin(__builtin_amdgcn_exp2f)
  return __builtin_amdgcn_exp2f(x);
#else
  return exp2f(x);
#endif
}
static __device__ __forceinline__ float fast_rcp(float x) {
  return __builtin_amdgcn_rcpf(x);
}
static __device__ __forceinline__ short f2bf(float f) {  // RTNE fp32->bf16
  unsigned u = __builtin_bit_cast(unsigned, f);
  u = (u + 0x7FFFu + ((u >> 16) & 1u)) >> 16;
  return (short)u;
}
static __device__ __forceinline__ unsigned pk2bf(float a, float b) {  // lo=a hi=b
#if __has_builtin(__builtin_amdgcn_cvt_pk_bf16_f32)
  auto v = __builtin_amdgcn_cvt_pk_bf16_f32(a, b);
  return __builtin_bit_cast(unsigned, v);
#else
  return (unsigned)(unsigned short)f2bf(a) | ((unsigned)(unsigned short)f2bf(b) << 16);
#endif
}
static __device__ __forceinline__ short8 pk8(float4v a, float4v b) {
  uint4v u = {pk2bf(a[0], a[1]), pk2bf(a[2], a[3]),
              pk2bf(b[0], b[1]), pk2bf(b[2], b[3])};
  return __builtin_bit_cast(short8, u);
}
static __device__ __forceinline__ short8 loadw8(const float* __restrict__ p) {
  short8 r;
  #pragma unroll
  for (int j = 0; j < 8; ++j) r[j] = f2bf(p[j]);
  return r;
}

// LDS blocks (short indices). Block = 2048 shorts (16 rows x 128 k bf16).
// Frag-linear: addr(row, k) = (k>>5)*512 + ((k>>3)&3)*128 + row*8 + (k&7);
// reader lane l, kstep s does b128 at s*512 + l*8 (conflict-free).
#define XB   0
#define H0B  4096
#define H1B  8192
#define BLK  2048

__global__ __launch_bounds__(512, 2) void gru_scan(
    const float* __restrict__ x,
    const float* __restrict__ Wih0, const float* __restrict__ Whh0,
    const float* __restrict__ bih0, const float* __restrict__ bhh0,
    const float* __restrict__ Wih1, const float* __restrict__ Whh1,
    const float* __restrict__ bih1, const float* __restrict__ bhh1,
    float* __restrict__ out) {
  __shared__ alignas(16) short Abuf[12288];  // 24 KB

  const int tid   = threadIdx.x;
  const int wave  = tid >> 6;
  const int lane  = tid & 63;
  const int lc    = lane & 15;
  const int quad  = lane >> 4;
  const int q8    = quad * 8;
  const int lane8 = lane * 8;
  const int bbase = blockIdx.x * 16;

  const int wgrp = wave >> 2;     // 0 = layer0 waves, 1 = layer1 waves
  const int w4   = wave & 3;

  const float* Wi = wgrp ? Wih1 : Wih0;
  const float* Wh = wgrp ? Whh1 : Whh0;
  const float* bi = wgrp ? bih1 : bih0;
  const float* bh = wgrp ? bhh1 : bhh0;

  // ---- stationary weight fragments: ONE layer, 2 unit-groups -------------
  short8 fxr[2][4], fxz[2][4], fxn[2][4];   // input-side (Wih)
  short8 fhr[2][4], fhz[2][4], fhn[2][4];   // hidden-side (Whh)
  float kr[2], kz[2], ki[2], kh[2];
  const float nL  = -1.44269504088896f;     // -log2(e)
  const float n2L = -2.88539008177793f;     // -2*log2(e)
  #pragma unroll
  for (int G = 0; G < 2; ++G) {
    const int c = 32 * w4 + 16 * G + lc;    // unit (column) this lane owns
    #pragma unroll
    for (int s = 0; s < 4; ++s) {
      const int k = 32 * s + q8;
      fxr[G][s] = loadw8(Wi + (c)       * Hd + k);
      fxz[G][s] = loadw8(Wi + (128 + c) * Hd + k);
      fxn[G][s] = loadw8(Wi + (256 + c) * Hd + k);
      fhr[G][s] = loadw8(Wh + (c)       * Hd + k);
      fhz[G][s] = loadw8(Wh + (128 + c) * Hd + k);
      fhn[G][s] = loadw8(Wh + (256 + c) * Hd + k);
    }
    kr[G] = nL  * (bi[c] + bh[c]);
    kz[G] = nL  * (bi[128 + c] + bh[128 + c]);
    ki[G] = n2L * bi[256 + c];
    kh[G] = n2L * bh[256 + c];
  }

  // LDS bases per wave-group
  const int hsel = wgrp ? H1B : H0B;   // h-part read + h write (own layer)
  const int isel = wgrp ? H0B : XB;    // input-part read

  // h-write offsets (frag layout, k = unit): u>>5 == w4 for our groups
  int hw[2];
  #pragma unroll
  for (int G = 0; G < 2; ++G)
    hw[G] = w4 * 512 + (2 * G + (lc >> 3)) * 128 + (lc & 7);

  // x staging (L0 waves only, 256 threads, 8 shorts each -> one b128 store)
  const int xrow  = tid >> 4;           // valid for tid < 256
  const int xk0   = (tid & 15) * 8;
  const int xwoff = (xk0 >> 5) * 512 + ((xk0 >> 3) & 3) * 128 + xrow * 8;
  const float* xg = x + (size_t)(bbase + (xrow & 15)) * (Tlen * Hd) + xk0;

  // ---- prologue ----------------------------------------------------------
  {
    int* zb = (int*)Abuf;               // zero H0/H1 blocks: dwords [2048,6144)
    #pragma unroll
    for (int i = 0; i < 8; ++i) zb[2048 + tid + 512 * i] = 0;
    if (wgrp == 0) {                    // stage x(0)->X[0], x(1)->X[1]
      const float4v a0 = *(const float4v*)(xg);
      const float4v b0 = *(const float4v*)(xg + 4);
      const float4v a1 = *(const float4v*)(xg + Hd);
      const float4v b1 = *(const float4v*)(xg + Hd + 4);
      *(short8*)&Abuf[XB + xwoff]       = pk8(a0, b0);
      *(short8*)&Abuf[XB + BLK + xwoff] = pk8(a1, b1);
    }
  }
  __syncthreads();

  const float4v Z4 = {0.f, 0.f, 0.f, 0.f};
  float4v ar[2], az[2], an[2], ah[2];
  float4v hp[2] = {Z4, Z4};
  #pragma unroll
  for (int G = 0; G < 2; ++G) { ar[G] = Z4; az[G] = Z4; an[G] = Z4; ah[G] = Z4; }

  // pre-loop (L0 only): iMFMA gi(0) from X[0]. L1 accs init in A(0).
  if (wgrp == 0) {
    #pragma unroll
    for (int s = 0; s < 4; ++s) {
      const short8 a = *(const short8*)&Abuf[XB + s * 512 + lane8];
      #pragma unroll
      for (int G = 0; G < 2; ++G) {
        ar[G] = MFMA16(a, fxr[G][s], ar[G]);
        az[G] = MFMA16(a, fxz[G][s], az[G]);
        an[G] = MFMA16(a, fxn[G][s], an[G]);
      }
    }
  }

  // ---- main loop: Tlen+3 iterations (L1 drains at t=Tlen+2) --------------
  for (int t = 0; t < Tlen + 3; ++t) {
    const int par  = (t & 1) * BLK;
    const int parx = BLK - par;
    float4v xv0, xv1;

    // ================= region A =================
    if (wgrp == 0) {
      // L0-P1(t): 24 hMFMA reading h0(t-1) @ H0B+parx; prefetch x(t+2)
      const int tn = (t + 2 < Tlen) ? (t + 2) : (Tlen - 1);
      xv0 = *(const float4v*)(xg + (size_t)tn * Hd);
      xv1 = *(const float4v*)(xg + (size_t)tn * Hd + 4);
      const int hrd = hsel + parx;
      #pragma unroll
      for (int s = 0; s < 4; ++s) {
        const short8 a = *(const short8*)&Abuf[hrd + s * 512 + lane8];
        #pragma unroll
        for (int G = 0; G < 2; ++G) {
          ar[G] = MFMA16(a, fhr[G][s], ar[G]);
          az[G] = MFMA16(a, fhz[G][s], az[G]);
          ah[G] = MFMA16(a, fhn[G][s], ah[G]);
        }
      }
    } else {
      // L1-P2'(s=t-3): gates -> h1(s) @ H1B+parx; iMFMA(s+1) from H0B+par
      if (t >= 3) {
        const int wr = hsel + parx;
        #pragma unroll
        for (int G = 0; G < 2; ++G) {
          #pragma unroll
          for (int i = 0; i < 4; ++i) {
            const float er = fast_exp2(fmaf(ar[G][i], nL, kr[G]));
            const float rr = fast_rcp(1.0f + er);
            const float ez = fast_exp2(fmaf(az[G][i], nL, kz[G]));
            const float zz = fast_rcp(1.0f + ez);
            float vv = fmaf(rr, fmaf(ah[G][i], n2L, kh[G]),
                            fmaf(an[G][i], n2L, ki[G]));
            vv = fminf(vv, 126.0f);
            const float e2 = fast_exp2(vv);
            const float nn = (1.0f - e2) * fast_rcp(1.0f + e2);
            const float hn = fmaf(zz, hp[G][i] - nn, nn);
            hp[G][i] = hn;
            Abuf[wr + hw[G] + (quad * 4 + i) * 8] = f2bf(hn);
          }
        }
      }
      const int ird = isel + par;
      #pragma unroll
      for (int G = 0; G < 2; ++G) { ar[G] = Z4; az[G] = Z4; an[G] = Z4; ah[G] = Z4; }
      #pragma unroll
      for (int s = 0; s < 4; ++s) {
        const short8 a = *(const short8*)&Abuf[ird + s * 512 + lane8];
        #pragma unroll
        for (int G = 0; G < 2; ++G) {
          ar[G] = MFMA16(a, fxr[G][s], ar[G]);
          az[G] = MFMA16(a, fxz[G][s], az[G]);
          an[G] = MFMA16(a, fxn[G][s], an[G]);
        }
      }
    }
    __syncthreads();

    // ================= region B =================
    if (wgrp == 0) {
      // L0-P2(t): stage x(t+2)->X@par; gates -> h0(t) @ H0B+par;
      //           iMFMA(t+1) from X@parx
      *(short8*)&Abuf[XB + par + xwoff] = pk8(xv0, xv1);
      if (t < Tlen) {
        const int wr = hsel + par;
        #pragma unroll
        for (int G = 0; G < 2; ++G) {
          #pragma unroll
          for (int i = 0; i < 4; ++i) {
            const float er = fast_exp2(fmaf(ar[G][i], nL, kr[G]));
            const float rr = fast_rcp(1.0f + er);
            const float ez = fast_exp2(fmaf(az[G][i], nL, kz[G]));
            const float zz = fast_rcp(1.0f + ez);
            float vv = fmaf(rr, fmaf(ah[G][i], n2L, kh[G]),
                            fmaf(an[G][i], n2L, ki[G]));
            vv = fminf(vv, 126.0f);
            const float e2 = fast_exp2(vv);
            const float nn = (1.0f - e2) * fast_rcp(1.0f + e2);
            const float hn = fmaf(zz, hp[G][i] - nn, nn);
            hp[G][i] = hn;
            Abuf[wr + hw[G] + (quad * 4 + i) * 8] = f2bf(hn);
          }
        }
      }
      const int ird = isel + parx;
      #pragma unroll
      for (int G = 0; G < 2; ++G) { ar[G] = Z4; az[G] = Z4; an[G] = Z4; ah[G] = Z4; }
      #pragma unroll
      for (int s = 0; s < 4; ++s) {
        const short8 a = *(const short8*)&Abuf[ird + s * 512 + lane8];
        #pragma unroll
        for (int G = 0; G < 2; ++G) {
          ar[G] = MFMA16(a, fxr[G][s], ar[G]);
          az[G] = MFMA16(a, fxz[G][s], az[G]);
          an[G] = MFMA16(a, fxn[G][s], an[G]);
        }
      }
    } else {
      // L1-P1'(s=t-2): 24 hMFMA reading h1(s-1) @ H1B+parx
      const int hrd = hsel + parx;
      #pragma unroll
      for (int s = 0; s < 4; ++s) {
        const short8 a = *(const short8*)&Abuf[hrd + s * 512 + lane8];
        #pragma unroll
        for (int G = 0; G < 2; ++G) {
          ar[G] = MFMA16(a, fhr[G][s], ar[G]);
          az[G] = MFMA16(a, fhz[G][s], az[G]);
          ah[G] = MFMA16(a, fhn[G][s], ah[G]);
        }
      }
    }
    __syncthreads();
  }

  // ---- output: L0 waves hold h0(T-1), L1 waves hold h1(T-1) --------------
  #pragma unroll
  for (int G = 0; G < 2; ++G) {
    const int u = 32 * w4 + 16 * G + lc;
    #pragma unroll
    for (int i = 0; i < 4; ++i) {
      const int b = bbase + quad * 4 + i;
      out[wgrp * (Bsz * Hd) + b * Hd + u] = hp[G][i];
    }
  }
}

extern "C" void kernel_launch(void* const* d_in, const int* in_sizes, int n_in,
                              void* d_out, int out_size, void* d_ws, size_t ws_size,
                              hipStream_t stream) {
  (void)in_sizes; (void)n_in; (void)out_size; (void)d_ws; (void)ws_size;
  gru_scan<<<4, 512, 0, stream>>>(
      (const float*)d_in[0],
      (const float*)d_in[1], (const float*)d_in[2],
      (const float*)d_in[3], (const float*)d_in[4],
      (const float*)d_in[5], (const float*)d_in[6],
      (const float*)d_in[7], (const float*)d_in[8],
      (float*)d_out);
}

// Round 5
// 8687.959 us; speedup vs baseline: 1.7199x; 1.7199x over previous
//
#include <hip/hip_runtime.h>

// GRU scan, 2 layers, B=64 T=4096 D=H=128 — layer-specialized waves.
// 4 persistent WGs x 16 batch rows x 512 threads (8 waves).
// Waves 0-3 compute layer 0, waves 4-7 compute layer 1 (skew 2 steps).
// Each wave owns 2 unit-groups (32 hidden units): 96 weight frags
// stationary in VGPR/AGPR.
//
// v6 = v1 (7030us, best) with ONE straight-line reorder: gates + h-write
// move from P2 into P1, directly after the hMFMA block (same-wave dep,
// no barrier required between them).
//   P1'(t): 24 hMFMA -> gates(t) -> h write @par      [MFMA then VALU]
//   P2'(t): x stage @par + 24 iMFMA(t+1) @parx        [pure MFMA]
// Rationale: in v1 all waves phase-lock at the mid-barrier right after
// their MFMAs, draining the MFMA pipe, then contend on VALU together in
// P2. With gates in P1', wave A's gate VALU overlaps wave B's hMFMA tail
// (m114: cross-wave MFMA||VALU co-issue). Round-4 lesson honored: all
// waves' gate phases still COINCIDE (one gate-wall per step, not two).
// Rounds 1-3 lessons: two barriers kept; no hand-interleave; linear LDS.
// Hazards (2-buffer parity): h@par written P1'(t), read P1'(t+1)@parx
// (2 barriers); L1 iMFMA reads H0@parx(t)=h0(t-1) from P1'(t-1) (2
// barriers); X staged P2'(t)@par, read P2'(t+1)@parx (2 barriers).

#define Tlen 4096
#define Hd   128
#define Bsz  64

typedef __attribute__((ext_vector_type(8))) short short8;     // 8 bf16
typedef __attribute__((ext_vector_type(4))) short short4v;    // 4 bf16
typedef __attribute__((ext_vector_type(4))) float float4v;
typedef __attribute__((ext_vector_type(2))) unsigned int uint2v;

#define MFMA16(a, b, c) __builtin_amdgcn_mfma_f32_16x16x32_bf16((a), (b), (c), 0, 0, 0)

static __device__ __forceinline__ float fast_exp2(float x) {
#if __has_builtin(__builtin_amdgcn_exp2f)
  return __builtin_amdgcn_exp2f(x);
#else
  return exp2f(x);
#endif
}
static __device__ __forceinline__ float fast_rcp(float x) {
  return __builtin_amdgcn_rcpf(x);
}
static __device__ __forceinline__ short f2bf(float f) {  // RTNE fp32->bf16
  unsigned u = __builtin_bit_cast(unsigned, f);
  u = (u + 0x7FFFu + ((u >> 16) & 1u)) >> 16;
  return (short)u;
}
static __device__ __forceinline__ unsigned pk2bf(float a, float b) {  // lo=a hi=b
#if __has_builtin(__builtin_amdgcn_cvt_pk_bf16_f32)
  auto v = __builtin_amdgcn_cvt_pk_bf16_f32(a, b);
  return __builtin_bit_cast(unsigned, v);
#else
  return (unsigned)(unsigned short)f2bf(a) | ((unsigned)(unsigned short)f2bf(b) << 16);
#endif
}
static __device__ __forceinline__ short8 loadw8(const float* __restrict__ p) {
  short8 r;
  #pragma unroll
  for (int j = 0; j < 8; ++j) r[j] = f2bf(p[j]);
  return r;
}

// LDS blocks (short indices). Block = 2048 shorts (16 rows x 128 k bf16).
// Frag-linear: addr(row, k) = (k>>5)*512 + ((k>>3)&3)*128 + row*8 + (k&7);
// reader lane l, kstep s does b128 at s*512 + l*8 (conflict-free).
#define XB   0
#define H0B  4096
#define H1B  8192
#define BLK  2048

__global__ __launch_bounds__(512, 2) void gru_scan(
    const float* __restrict__ x,
    const float* __restrict__ Wih0, const float* __restrict__ Whh0,
    const float* __restrict__ bih0, const float* __restrict__ bhh0,
    const float* __restrict__ Wih1, const float* __restrict__ Whh1,
    const float* __restrict__ bih1, const float* __restrict__ bhh1,
    float* __restrict__ out) {
  __shared__ alignas(16) short Abuf[12288];  // 24 KB

  const int tid   = threadIdx.x;
  const int wave  = tid >> 6;
  const int lane  = tid & 63;
  const int lc    = lane & 15;
  const int quad  = lane >> 4;
  const int q8    = quad * 8;
  const int lane8 = lane * 8;
  const int bbase = blockIdx.x * 16;

  const int wgrp = wave >> 2;     // 0 = layer0 waves, 1 = layer1 waves
  const int w4   = wave & 3;

  const float* Wi = wgrp ? Wih1 : Wih0;
  const float* Wh = wgrp ? Whh1 : Whh0;
  const float* bi = wgrp ? bih1 : bih0;
  const float* bh = wgrp ? bhh1 : bhh0;

  // ---- stationary weight fragments: ONE layer, 2 unit-groups -------------
  short8 fxr[2][4], fxz[2][4], fxn[2][4];   // input-side (Wih)
  short8 fhr[2][4], fhz[2][4], fhn[2][4];   // hidden-side (Whh)
  float kr[2], kz[2], ki[2], kh[2];
  const float nL  = -1.44269504088896f;     // -log2(e)
  const float n2L = -2.88539008177793f;     // -2*log2(e)
  #pragma unroll
  for (int G = 0; G < 2; ++G) {
    const int c = 32 * w4 + 16 * G + lc;    // unit (column) this lane owns
    #pragma unroll
    for (int s = 0; s < 4; ++s) {
      const int k = 32 * s + q8;
      fxr[G][s] = loadw8(Wi + (c)       * Hd + k);
      fxz[G][s] = loadw8(Wi + (128 + c) * Hd + k);
      fxn[G][s] = loadw8(Wi + (256 + c) * Hd + k);
      fhr[G][s] = loadw8(Wh + (c)       * Hd + k);
      fhz[G][s] = loadw8(Wh + (128 + c) * Hd + k);
      fhn[G][s] = loadw8(Wh + (256 + c) * Hd + k);
    }
    kr[G] = nL  * (bi[c] + bh[c]);
    kz[G] = nL  * (bi[128 + c] + bh[128 + c]);
    ki[G] = n2L * bi[256 + c];
    kh[G] = n2L * bh[256 + c];
  }

  // LDS bases per wave-group
  const int hsel = wgrp ? H1B : H0B;   // h-part read (P1) + h write
  const int isel = wgrp ? H0B : XB;    // input-part read (P2)

  // h-write offsets (frag layout, k = unit): u>>5 == w4 for our groups
  int hw[2];
  #pragma unroll
  for (int G = 0; G < 2; ++G)
    hw[G] = w4 * 512 + (2 * G + (lc >> 3)) * 128 + (lc & 7);

  // x staging slots: thread -> (row, k0..k0+3)
  const int xrow = tid >> 5;
  const int xk0  = 4 * (tid & 31);
  const int xwoff = (xk0 >> 5) * 512 + ((xk0 >> 3) & 3) * 128 + xrow * 8 + (xk0 & 7);
  const float* xg = x + (size_t)(bbase + xrow) * (Tlen * Hd) + xk0;

  // gate-validity window: L0 steps t in [0,T), L1 sigma=t-2 -> t in [2,T+2)
  const int glo = wgrp ? 2 : 0;
  const int ghi = glo + Tlen;

  // ---- prologue ----------------------------------------------------------
  {
    int* zb = (int*)Abuf;               // zero H0/H1 blocks: dwords [2048,6144)
    #pragma unroll
    for (int i = 0; i < 8; ++i) zb[2048 + tid + 512 * i] = 0;
    const float4v v0 = *(const float4v*)(xg);                 // x(0)
    const float4v v1 = *(const float4v*)(xg + Hd);            // x(1)
    uint2v p0 = {pk2bf(v0[0], v0[1]), pk2bf(v0[2], v0[3])};
    uint2v p1 = {pk2bf(v1[0], v1[1]), pk2bf(v1[2], v1[3])};
    *(short4v*)&Abuf[XB + xwoff]       = __builtin_bit_cast(short4v, p0);
    *(short4v*)&Abuf[XB + BLK + xwoff] = __builtin_bit_cast(short4v, p1);
  }
  __syncthreads();

  const float4v Z4 = {0.f, 0.f, 0.f, 0.f};
  float4v ar[2], az[2], an[2], ah[2];
  float4v hp[2] = {Z4, Z4};

  // prologue "P2(-1)": input-part MFMAs (L0: x(0) from X[0]; L1: zeros)
  #pragma unroll
  for (int G = 0; G < 2; ++G) { ar[G] = Z4; az[G] = Z4; an[G] = Z4; ah[G] = Z4; }
  #pragma unroll
  for (int s = 0; s < 4; ++s) {
    const short8 a = *(const short8*)&Abuf[isel + s * 512 + lane8];
    #pragma unroll
    for (int G = 0; G < 2; ++G) {
      ar[G] = MFMA16(a, fxr[G][s], ar[G]);
      az[G] = MFMA16(a, fxz[G][s], az[G]);
      an[G] = MFMA16(a, fxn[G][s], an[G]);
    }
  }

  // ---- main loop: T+2 iterations (2-step drain for layer 1) --------------
  for (int t = 0; t < Tlen + 2; ++t) {
    const int par  = (t & 1) * BLK;     // parity t block offset
    const int parx = BLK - par;         // parity (t+1) block offset

    // ---- P1': h-part MFMAs (24) + gates + h write + x(t+2) prefetch ----
    const int tn = (t + 2 < Tlen) ? (t + 2) : (Tlen - 1);
    const float4v xv = *(const float4v*)(xg + (size_t)tn * Hd);
    const int hrd = hsel + parx;
    #pragma unroll
    for (int s = 0; s < 4; ++s) {
      const short8 a = *(const short8*)&Abuf[hrd + s * 512 + lane8];
      #pragma unroll
      for (int G = 0; G < 2; ++G) {
        ar[G] = MFMA16(a, fhr[G][s], ar[G]);
        az[G] = MFMA16(a, fhz[G][s], az[G]);
        ah[G] = MFMA16(a, fhn[G][s], ah[G]);
      }
    }
    // gates(t): same-wave dependency on the accs above — no barrier needed.
    // While this wave runs gate VALU, the sibling wave's hMFMAs keep the
    // MFMA pipe busy.
    if (t >= glo && t < ghi) {
      const int wr = hsel + par;
      #pragma unroll
      for (int G = 0; G < 2; ++G) {
        #pragma unroll
        for (int i = 0; i < 4; ++i) {
          const float er = fast_exp2(fmaf(ar[G][i], nL, kr[G]));
          const float rr = fast_rcp(1.0f + er);
          const float ez = fast_exp2(fmaf(az[G][i], nL, kz[G]));
          const float zz = fast_rcp(1.0f + ez);
          float vv = fmaf(rr, fmaf(ah[G][i], n2L, kh[G]),
                          fmaf(an[G][i], n2L, ki[G]));
          vv = fminf(vv, 126.0f);
          const float e2 = fast_exp2(vv);
          const float nn = (1.0f - e2) * fast_rcp(1.0f + e2);
          const float hn = fmaf(zz, hp[G][i] - nn, nn);
          hp[G][i] = hn;
          Abuf[wr + hw[G] + (quad * 4 + i) * 8] = f2bf(hn);
        }
      }
    }
    __syncthreads();

    // ---- P2': x stage + input MFMAs for next step ----
    {  // stage x(t+2) into X[t&1] (dead buffer; consumed in P2'(t+1))
      uint2v pp = {pk2bf(xv[0], xv[1]), pk2bf(xv[2], xv[3])};
      *(short4v*)&Abuf[XB + par + xwoff] = __builtin_bit_cast(short4v, pp);
    }
    const int ird = isel + parx;
    #pragma unroll
    for (int G = 0; G < 2; ++G) { ar[G] = Z4; az[G] = Z4; an[G] = Z4; ah[G] = Z4; }
    #pragma unroll
    for (int s = 0; s < 4; ++s) {
      const short8 a = *(const short8*)&Abuf[ird + s * 512 + lane8];
      #pragma unroll
      for (int G = 0; G < 2; ++G) {
        ar[G] = MFMA16(a, fxr[G][s], ar[G]);
        az[G] = MFMA16(a, fxz[G][s], az[G]);
        an[G] = MFMA16(a, fxn[G][s], an[G]);
      }
    }
    __syncthreads();
  }

  // ---- output: L0 waves hold h0(T-1), L1 waves hold h1(T-1) --------------
  #pragma unroll
  for (int G = 0; G < 2; ++G) {
    const int u = 32 * w4 + 16 * G + lc;
    #pragma unroll
    for (int i = 0; i < 4; ++i) {
      const int b = bbase + quad * 4 + i;
      out[wgrp * (Bsz * Hd) + b * Hd + u] = hp[G][i];
    }
  }
}

extern "C" void kernel_launch(void* const* d_in, const int* in_sizes, int n_in,
                              void* d_out, int out_size, void* d_ws, size_t ws_size,
                              hipStream_t stream) {
  (void)in_sizes; (void)n_in; (void)out_size; (void)d_ws; (void)ws_size;
  gru_scan<<<4, 512, 0, stream>>>(
      (const float*)d_in[0],
      (const float*)d_in[1], (const float*)d_in[2],
      (const float*)d_in[3], (const float*)d_in[4],
      (const float*)d_in[5], (const float*)d_in[6],
      (const float*)d_in[7], (const float*)d_in[8],
      (float*)d_out);
}

// Round 6
// 7428.127 us; speedup vs baseline: 2.0116x; 1.1696x over previous
//
#include <hip/hip_runtime.h>

// GRU scan, 2 layers, B=64 T=4096 D=H=128 — LAYER-SPLIT workgroups.
// 8 persistent WGs = 4 row-blocks x 2 layers; 512 threads (8 waves) each.
// Each wave owns 16 units of its WG's layer: per step 12 hMFMA + 12 iMFMA
// + 4 gate-elems/lane — HALF of the v1 per-wave load. v1 (7030us) used
// only 4 CUs with both pipes near-saturated per SIMD (MFMA 2390cy + VALU
// 3340cy per 4117cy step); rounds 1-5 proved intra-CU rescheduling can't
// help. This doubles the CUs instead.
//
// Cross-WG dataflow: L0-WG(rb) writes h0(t) (the same f2bf bf16 values it
// puts in its own LDS) to a global ring FIFO slot t%16 (4KB/step, stays in
// L2/LLC); L1-WG(rb) stages slot sigma+2 into its input LDS each step
// (mirrors v1's x staging). Sync: agent-scope release/acquire flags.
//   done0[rb]: last t with h0 FIFO complete (publish every 2 steps + final)
//   done1[rb]: last slot staged by consumer   (publish every 4 steps)
// Consumer gate: done0 >= sigma+2 -> lag >= 3. Producer flow check every
// 4 steps: done1 >= t-13 (ring 16). Blocked-producer => sigma < t-11,
// blocked-consumer => sigma > t-4: mutually exclusive -> no deadlock.
// Flag loads issue before the hMFMA block, are checked after it (latency
// hidden); FIFO data load latency hides under gates (~1200cy).
// Per-WG schedule = v1's two-barrier body verbatim (rounds 1-5 lessons:
// no barrier merge, no hand-interleave, no antiphase, linear LDS).
//
// Workspace: flags (32B) at d_ws; FIFO ring 4rb x 16 x 4KB = 256KB at
// d_ws+256. kernel_launch memsets flags to -1 (captured in graph).

#define Tlen  4096
#define Hd    128
#define Bsz   64
#define DEPTH 16

typedef __attribute__((ext_vector_type(8))) short short8;     // 8 bf16
typedef __attribute__((ext_vector_type(4))) short short4v;    // 4 bf16
typedef __attribute__((ext_vector_type(4))) float float4v;
typedef __attribute__((ext_vector_type(2))) unsigned int uint2v;

#define MFMA16(a, b, c) __builtin_amdgcn_mfma_f32_16x16x32_bf16((a), (b), (c), 0, 0, 0)

static __device__ __forceinline__ float fast_exp2(float x) {
#if __has_builtin(__builtin_amdgcn_exp2f)
  return __builtin_amdgcn_exp2f(x);
#else
  return exp2f(x);
#endif
}
static __device__ __forceinline__ float fast_rcp(float x) {
  return __builtin_amdgcn_rcpf(x);
}
static __device__ __forceinline__ short f2bf(float f) {  // RTNE fp32->bf16
  unsigned u = __builtin_bit_cast(unsigned, f);
  u = (u + 0x7FFFu + ((u >> 16) & 1u)) >> 16;
  return (short)u;
}
static __device__ __forceinline__ unsigned pk2bf(float a, float b) {  // lo=a hi=b
#if __has_builtin(__builtin_amdgcn_cvt_pk_bf16_f32)
  auto v = __builtin_amdgcn_cvt_pk_bf16_f32(a, b);
  return __builtin_bit_cast(unsigned, v);
#else
  return (unsigned)(unsigned short)f2bf(a) | ((unsigned)(unsigned short)f2bf(b) << 16);
#endif
}
static __device__ __forceinline__ short8 loadw8(const float* __restrict__ p) {
  short8 r;
  #pragma unroll
  for (int j = 0; j < 8; ++j) r[j] = f2bf(p[j]);
  return r;
}
static __device__ __forceinline__ int flag_acq(const int* p) {
  return __hip_atomic_load(p, __ATOMIC_ACQUIRE, __HIP_MEMORY_SCOPE_AGENT);
}
static __device__ __forceinline__ void flag_rel(int* p, int v) {
  __hip_atomic_store(p, v, __ATOMIC_RELEASE, __HIP_MEMORY_SCOPE_AGENT);
}

// LDS: H dbuf [0,4096) shorts, IN dbuf [4096,8192). Block = 2048 shorts
// (16 rows x 128 k bf16), frag-linear:
// addr(row,k) = (k>>5)*512 + ((k>>3)&3)*128 + row*8 + (k&7);
// reader lane l, kstep s does b128 at s*512 + l*8 (conflict-free).
#define HB   0
#define INB  4096
#define BLK  2048

__global__ __launch_bounds__(512, 2) void gru_scan(
    const float* __restrict__ x,
    const float* __restrict__ Wih0, const float* __restrict__ Whh0,
    const float* __restrict__ bih0, const float* __restrict__ bhh0,
    const float* __restrict__ Wih1, const float* __restrict__ Whh1,
    const float* __restrict__ bih1, const float* __restrict__ bhh1,
    float* __restrict__ out, int* __restrict__ flags,
    short* __restrict__ fifo) {
  __shared__ alignas(16) short Abuf[8192];  // 16 KB

  const int tid   = threadIdx.x;
  const int wave  = tid >> 6;
  const int lane  = tid & 63;
  const int lc    = lane & 15;
  const int quad  = lane >> 4;
  const int q8    = quad * 8;
  const int lane8 = lane * 8;
  const int rb    = blockIdx.x & 3;     // row-block (16 batch rows)
  const int lyr   = blockIdx.x >> 2;    // 0 = layer0 WG, 1 = layer1 WG
  const int bbase = rb * 16;

  const float* Wi = lyr ? Wih1 : Wih0;
  const float* Wh = lyr ? Whh1 : Whh0;
  const float* bi = lyr ? bih1 : bih0;
  const float* bh = lyr ? bhh1 : bhh0;

  // ---- stationary weight fragments: 16 units per wave ---------------------
  short8 fxr[4], fxz[4], fxn[4];   // input-side (Wih)
  short8 fhr[4], fhz[4], fhn[4];   // hidden-side (Whh)
  const float nL  = -1.44269504088896f;     // -log2(e)
  const float n2L = -2.88539008177793f;     // -2*log2(e)
  const int c = 16 * wave + lc;             // unit (column) this lane owns
  #pragma unroll
  for (int s = 0; s < 4; ++s) {
    const int k = 32 * s + q8;
    fxr[s] = loadw8(Wi + (c)       * Hd + k);
    fxz[s] = loadw8(Wi + (128 + c) * Hd + k);
    fxn[s] = loadw8(Wi + (256 + c) * Hd + k);
    fhr[s] = loadw8(Wh + (c)       * Hd + k);
    fhz[s] = loadw8(Wh + (128 + c) * Hd + k);
    fhn[s] = loadw8(Wh + (256 + c) * Hd + k);
  }
  const float kr = nL  * (bi[c] + bh[c]);
  const float kz = nL  * (bi[128 + c] + bh[128 + c]);
  const float ki = n2L * bi[256 + c];
  const float kh = n2L * bh[256 + c];

  // h-write offset (frag layout, k = unit): value (row=4q+i) at
  // HB+par + hwb + (quad*4+i)*8
  const int hwb = (wave >> 1) * 512 + ((wave & 1) * 2 + (lc >> 3)) * 128 + (lc & 7);

  // staging thread mapping: thread -> (row, k0..k0+3), shared by x / FIFO
  const int srow  = tid >> 5;
  const int sk0   = 4 * (tid & 31);
  const int swoff = (sk0 >> 5) * 512 + ((sk0 >> 3) & 3) * 128 + srow * 8 + (sk0 & 7);
  const float* xg = x + (size_t)(bbase + srow) * (Tlen * Hd) + sk0;  // L0 only

  short* fifo_rb = fifo + (size_t)rb * (DEPTH * BLK);
  int* d0 = flags + rb;        // producer progress
  int* d1 = flags + 4 + rb;    // consumer progress

  // ---- prologue -----------------------------------------------------------
  {
    int* zb = (int*)Abuf;      // zero H dbuf: dwords [0, 2048)
    #pragma unroll
    for (int i = 0; i < 4; ++i) zb[tid + 512 * i] = 0;
    if (lyr == 0) {            // stage x(0)->IN[0], x(1)->IN[1]
      const float4v v0 = *(const float4v*)(xg);
      const float4v v1 = *(const float4v*)(xg + Hd);
      uint2v p0 = {pk2bf(v0[0], v0[1]), pk2bf(v0[2], v0[3])};
      uint2v p1 = {pk2bf(v1[0], v1[1]), pk2bf(v1[2], v1[3])};
      *(short4v*)&Abuf[INB + swoff]       = __builtin_bit_cast(short4v, p0);
      *(short4v*)&Abuf[INB + BLK + swoff] = __builtin_bit_cast(short4v, p1);
    } else {                   // wait for h0(0),h0(1); stage slots 0,1
      while (flag_acq(d0) < 1) __builtin_amdgcn_s_sleep(8);
      const short4v h0a = *(const short4v*)(fifo_rb + 0 * BLK + srow * 128 + sk0);
      const short4v h0b = *(const short4v*)(fifo_rb + 1 * BLK + srow * 128 + sk0);
      *(short4v*)&Abuf[INB + swoff]       = h0a;
      *(short4v*)&Abuf[INB + BLK + swoff] = h0b;
    }
  }
  __syncthreads();

  const float4v Z4 = {0.f, 0.f, 0.f, 0.f};
  float4v ar = Z4, az = Z4, an = Z4, ah = Z4;
  float4v hp = Z4;

  // prologue "P2(-1)": input-part MFMAs for step 0 from IN[0]
  #pragma unroll
  for (int s = 0; s < 4; ++s) {
    const short8 a = *(const short8*)&Abuf[INB + s * 512 + lane8];
    ar = MFMA16(a, fxr[s], ar);
    az = MFMA16(a, fxz[s], az);
    an = MFMA16(a, fxn[s], an);
  }

  // ---- main loop: Tlen steps ----------------------------------------------
  for (int t = 0; t < Tlen; ++t) {
    const int par  = (t & 1) * BLK;     // parity t (writes)
    const int parx = BLK - par;         // parity t+1 (reads)
    const int tn   = (t + 2 < Tlen) ? (t + 2) : (Tlen - 1);

    // ---- P1: flags + input prefetch + 12 hMFMA ----
    float4v xv;
    short4v hv;
    int fd = 0x7fffffff;                // flag value (checked after hMFMA)
    if (lyr == 0) {
      xv = *(const float4v*)(xg + (size_t)tn * Hd);
      if ((t & 3) == 0) fd = flag_acq(d1);                   // flow control
      if ((t & 1) == 0 && t > 0 && tid == 0) flag_rel(d0, t - 1);
    } else {
      fd = flag_acq(d0);                                     // data ready?
      if ((t & 3) == 0 && tid == 0) flag_rel(d1, t + 1);
    }
    const int hrd = HB + parx;
    #pragma unroll
    for (int s = 0; s < 4; ++s) {
      const short8 a = *(const short8*)&Abuf[hrd + s * 512 + lane8];
      ar = MFMA16(a, fhr[s], ar);
      az = MFMA16(a, fhz[s], az);
      ah = MFMA16(a, fhn[s], ah);
    }
    if (lyr == 0) {
      if ((t & 3) == 0) {               // ring slot t..t+3 reuse guard
        while (fd < t - 13) { __builtin_amdgcn_s_sleep(8); fd = flag_acq(d1); }
      }
    } else {
      while (fd < tn) { __builtin_amdgcn_s_sleep(8); fd = flag_acq(d0); }
      hv = *(const short4v*)(fifo_rb + (size_t)(tn & (DEPTH - 1)) * BLK +
                             srow * 128 + sk0);
    }
    __syncthreads();

    // ---- P2: gates + h/FIFO write + input stage + 12 iMFMA ----
    {
      const int wr = HB + par;
      const int fw = (t & (DEPTH - 1)) * BLK;
      #pragma unroll
      for (int i = 0; i < 4; ++i) {
        const float er = fast_exp2(fmaf(ar[i], nL, kr));
        const float rr = fast_rcp(1.0f + er);
        const float ez = fast_exp2(fmaf(az[i], nL, kz));
        const float zz = fast_rcp(1.0f + ez);
        float vv = fmaf(rr, fmaf(ah[i], n2L, kh), fmaf(an[i], n2L, ki));
        vv = fminf(vv, 126.0f);
        const float e2 = fast_exp2(vv);
        const float nn = (1.0f - e2) * fast_rcp(1.0f + e2);
        const float hn = fmaf(zz, hp[i] - nn, nn);
        hp[i] = hn;
        const short hb = f2bf(hn);
        Abuf[wr + hwb + (quad * 4 + i) * 8] = hb;
        if (lyr == 0) fifo_rb[fw + (quad * 4 + i) * 128 + c] = hb;
      }
    }
    {  // stage input(t+2) into IN[t&1] (dead buffer; consumed at t+1)
      if (lyr == 0) {
        uint2v pp = {pk2bf(xv[0], xv[1]), pk2bf(xv[2], xv[3])};
        *(short4v*)&Abuf[INB + par + swoff] = __builtin_bit_cast(short4v, pp);
      } else {
        *(short4v*)&Abuf[INB + par + swoff] = hv;
      }
    }
    // input-part MFMAs for next step (re-init accs)
    const int ird = INB + parx;
    ar = Z4; az = Z4; an = Z4; ah = Z4;
    #pragma unroll
    for (int s = 0; s < 4; ++s) {
      const short8 a = *(const short8*)&Abuf[ird + s * 512 + lane8];
      ar = MFMA16(a, fxr[s], ar);
      az = MFMA16(a, fxz[s], az);
      an = MFMA16(a, fxn[s], an);
    }
    __syncthreads();
  }

  // final publish so the consumer can drain (stores drained by last barrier)
  if (lyr == 0 && tid == 0) flag_rel(d0, Tlen - 1);

  // ---- output: each WG writes its layer's h(T-1) --------------------------
  #pragma unroll
  for (int i = 0; i < 4; ++i) {
    const int b = bbase + quad * 4 + i;
    out[lyr * (Bsz * Hd) + b * Hd + c] = hp[i];
  }
}

extern "C" void kernel_launch(void* const* d_in, const int* in_sizes, int n_in,
                              void* d_out, int out_size, void* d_ws, size_t ws_size,
                              hipStream_t stream) {
  (void)in_sizes; (void)n_in; (void)out_size; (void)ws_size;
  // flags (8 ints) -> -1; FIFO ring lives at d_ws+256 (4rb x 16 x 4KB).
  hipMemsetAsync(d_ws, 0xFF, 64, stream);
  gru_scan<<<8, 512, 0, stream>>>(
      (const float*)d_in[0],
      (const float*)d_in[1], (const float*)d_in[2],
      (const float*)d_in[3], (const float*)d_in[4],
      (const float*)d_in[5], (const float*)d_in[6],
      (const float*)d_in[7], (const float*)d_in[8],
      (float*)d_out, (int*)d_ws, (short*)((char*)d_ws + 256));
}